// Round 1
// baseline (43.485 us; speedup 1.0000x reference)
//
#include <hip/hip_runtime.h>

// LIF recurrence: u = u/2 + x_t; s = (u >= 1); u = s ? 0 : u.
// x: [B, T, N] fp32, out: [B, T, N] fp32 spikes. Chains independent over (b, n).
// Memory-bound: 256 MiB total traffic -> ~40 us floor at 6.3 TB/s.

#ifndef LIF_T
#define LIF_T 32
#endif
#ifndef LIF_N
#define LIF_N 8192
#endif

__global__ __launch_bounds__(256) void lif_fwd_kernel(const float4* __restrict__ x,
                                                      float4* __restrict__ out,
                                                      int n_chain4) {
    const int NV = LIF_N / 4;  // float4 columns per row = 2048
    int i = blockIdx.x * blockDim.x + threadIdx.x;
    if (i >= n_chain4) return;

    int b = i / NV;
    int c = i - b * NV;
    int base = (b * LIF_T) * NV + c;  // max ~8.4M float4 -> fits int

    float ux = 0.f, uy = 0.f, uz = 0.f, uw = 0.f;

#pragma unroll 4
    for (int t = 0; t < LIF_T; ++t) {
        float4 xt = x[base + t * NV];

        // leaky integrate: u = u*0.5 + x  (u*0.5 exact; single rounded add == ref's u/2 + x)
        ux = ux * 0.5f + xt.x;
        uy = uy * 0.5f + xt.y;
        uz = uz * 0.5f + xt.z;
        uw = uw * 0.5f + xt.w;

        float4 s;
        s.x = (ux >= 1.0f) ? 1.0f : 0.0f;
        s.y = (uy >= 1.0f) ? 1.0f : 0.0f;
        s.z = (uz >= 1.0f) ? 1.0f : 0.0f;
        s.w = (uw >= 1.0f) ? 1.0f : 0.0f;

        // hard reset to 0 when fired (V_RESET = 0)
        ux = (ux >= 1.0f) ? 0.0f : ux;
        uy = (uy >= 1.0f) ? 0.0f : uy;
        uz = (uz >= 1.0f) ? 0.0f : uz;
        uw = (uw >= 1.0f) ? 0.0f : uw;

        out[base + t * NV] = s;
    }
}

extern "C" void kernel_launch(void* const* d_in, const int* in_sizes, int n_in,
                              void* d_out, int out_size, void* d_ws, size_t ws_size,
                              hipStream_t stream) {
    const float* x = (const float*)d_in[0];
    float* out = (float*)d_out;

    int total = in_sizes[0];                 // B*T*N
    int B = total / (LIF_T * LIF_N);         // 128
    int n_chain4 = B * (LIF_N / 4);          // 262144

    int block = 256;
    int grid = (n_chain4 + block - 1) / block;  // 1024
    lif_fwd_kernel<<<grid, block, 0, stream>>>((const float4*)x, (float4*)out, n_chain4);
}